// Round 9
// baseline (51.058 us; speedup 1.0000x reference)
//
#include <hip/hip_runtime.h>

#define HID 64
#define NROWS 1036
#define KNOTS 256            // nearest-neighbor: 257 knots, p_j = j/256
#define NKNOT (KNOTS + 1)
#define CAP 1024             // bucket capacity (bench max ~190 for uniform input)
#define MAXCHUNK 2600

// u32-unit offsets inside the table:
#define W1_OFF 0                          // [j][h]  f16x2 {w1e0,w1e1}      (64 u32/j)
#define A2_OFF (NKNOT * 64)               // [j][r*32+hp] f16x2 a2 pairs    (128 u32/j)
#define EP_OFF (A2_OFF + NKNOT * 128)     // [j][h]  {b2r01,b2r23,(w3,B2)}  (192 u32/j)
#define W2F_OFF (EP_OFF + NKNOT * 192)    // W2 MFMA A-frags, 512 uint4
#define TBL_SZ (W2F_OFF + 2048)

__device__ __align__(16) unsigned TBL[TBL_SZ];
__device__ int binCnt[NKNOT];
__device__ int bucket[NKNOT * CAP];
__device__ int4 chunkTab[MAXCHUNK];       // {knot, bucketBase, validCnt, pad}
__device__ int gTotalChunks;

typedef _Float16 half2v __attribute__((ext_vector_type(2)));
typedef _Float16 half8  __attribute__((ext_vector_type(8)));
typedef float    f32x4  __attribute__((ext_vector_type(4)));

__device__ inline unsigned packh2(float a, float b) {
    half2v v; v.x = (_Float16)a; v.y = (_Float16)b;
    return __builtin_bit_cast(unsigned, v);
}
__device__ inline float2 up2(unsigned u) {
    half2v v = __builtin_bit_cast(half2v, u);
    return make_float2((float)v.x, (float)v.y);
}
__device__ inline float fdot2u(unsigned a, unsigned b, float c) {
#if defined(__has_builtin) && __has_builtin(__builtin_amdgcn_fdot2)
    return __builtin_amdgcn_fdot2(__builtin_bit_cast(half2v, a),
                                  __builtin_bit_cast(half2v, b), c, false);
#else
    half2v av = __builtin_bit_cast(half2v, a);
    half2v bv = __builtin_bit_cast(half2v, b);
    return fmaf((float)av.x, (float)bv.x, fmaf((float)av.y, (float)bv.y, c));
#endif
}
__device__ inline float tanh_fast(float x) {
    return 1.0f - __fdividef(2.0f, __expf(2.0f * x) + 1.0f);
}
__device__ inline int knot_of(float p) {
    int j = (int)fmaf(p, (float)KNOTS, 0.5f);
    return max(0, min(KNOTS, j));
}

// Build: one block per knot. g[1036] in LDS, fold into effective tables.
// Block 0 also zeros binCnt and packs the W2 MFMA A-fragments.
__global__ __launch_bounds__(256) void build_eff_kernel(
    const float* __restrict__ Wh1, const float* __restrict__ Bh1,
    const float* __restrict__ Wh2, const float* __restrict__ Bh2,
    const float* __restrict__ W1,  const float* __restrict__ W3,
    const float* __restrict__ W2,  const float* __restrict__ B2) {
    __shared__ float h[HID];
    __shared__ float g[NROWS];
    const int j = blockIdx.x;                      // 0..256
    const float p = (float)j / (float)KNOTS;
    const int t = threadIdx.x;
    if (j == 0) for (int i = t; i < NKNOT; i += 256) binCnt[i] = 0;
    if (t < HID) h[t] = tanhf(fmaf(p, Wh1[t], Bh1[t]));
    __syncthreads();
    for (int i = t; i < NROWS; i += 256) {
        const float4* row = (const float4*)(Wh2 + i * HID);
        float a0 = 0.f, a1 = 0.f, a2 = 0.f, a3 = 0.f;
        #pragma unroll
        for (int q = 0; q < 16; ++q) {
            float4 w = row[q];
            a0 = fmaf(w.x, h[4 * q + 0], a0);
            a1 = fmaf(w.y, h[4 * q + 1], a1);
            a2 = fmaf(w.z, h[4 * q + 2], a2);
            a3 = fmaf(w.w, h[4 * q + 3], a3);
        }
        g[i] = Bh2[i] + (a0 + a1) + (a2 + a3);
    }
    __syncthreads();
    // g: a1[r][c]=g[2r+c], b1[h][r]=g[8+4h+r], a2[r][k]=g[264+64r+k],
    //    b2[h][r]=g[520+4h+r], a3[r][k]=g[776+64r+k], b3[r]=g[1032+r]
    unsigned* tb = TBL;
    if (t < HID) {
        const int hh = t;
        const float* b1 = g + 8 + 4 * hh;
        float e0 = W1[2 * hh], e1 = W1[2 * hh + 1];
        #pragma unroll
        for (int r = 0; r < 4; ++r) {
            e0 = fmaf(b1[r], g[2 * r],     e0);
            e1 = fmaf(b1[r], g[2 * r + 1], e1);
        }
        tb[W1_OFF + j * 64 + hh] = packh2(e0, e1);
        float w3e = W3[hh];
        #pragma unroll
        for (int r = 0; r < 4; ++r)
            w3e = fmaf(g[1032 + r], g[776 + 64 * r + hh], w3e);
        tb[EP_OFF + j * 192 + hh * 3 + 0] = packh2(g[520 + 4 * hh],     g[520 + 4 * hh + 1]);
        tb[EP_OFF + j * 192 + hh * 3 + 1] = packh2(g[520 + 4 * hh + 2], g[520 + 4 * hh + 3]);
        tb[EP_OFF + j * 192 + hh * 3 + 2] = packh2(w3e, B2[hh]);
    }
    if (t < 128) {
        const int r = t >> 5, pp = t & 31;
        tb[A2_OFF + j * 128 + t] = packh2(g[264 + 64 * r + 2 * pp], g[264 + 64 * r + 2 * pp + 1]);
    }
    if (j == 0) {
        for (int q = t; q < 512; q += 256) {
            const int f = q >> 6, l = q & 63;
            const int kb = f >> 2, hb = f & 3;
            const int m = l & 15, k0 = (l >> 4) * 8;
            const float* src = W2 + (hb * 16 + m) * HID + kb * 32 + k0;
            half8 v;
            #pragma unroll
            for (int i = 0; i < 8; ++i) v[i] = (_Float16)src[i];
            ((uint4*)(tb + W2F_OFF))[q] = __builtin_bit_cast(uint4, v);
        }
    }
}

// Bin samples by knot (fused histogram+scatter).
__global__ __launch_bounds__(256) void scatter_kernel(const float* __restrict__ param, int n) {
    const int s = blockIdx.x * 256 + threadIdx.x;
    if (s >= n) return;
    const int j = knot_of(param[s]);
    const int pos = atomicAdd(&binCnt[j], 1);
    if (pos < CAP) bucket[j * CAP + pos] = s;
}

// Build compact chunk list: one block, 320 threads.
__global__ __launch_bounds__(320) void scan_kernel() {
    __shared__ int A[NKNOT];
    const int t = threadIdx.x;
    int cnt = 0;
    if (t < NKNOT) { cnt = binCnt[t]; A[t] = (cnt + 15) >> 4; }
    __syncthreads();
    for (int off = 1; off < NKNOT; off <<= 1) {
        int v = 0;
        if (t < NKNOT && t >= off) v = A[t - off];
        __syncthreads();
        if (t < NKNOT) A[t] += v;
        __syncthreads();
    }
    if (t < NKNOT) {
        const int nch = (cnt + 15) >> 4;
        const int off0 = A[t] - nch;            // exclusive prefix
        for (int c = 0; c < nch; ++c)
            chunkTab[off0 + c] = make_int4(t, t * CAP + 16 * c, min(16, cnt - 16 * c), 0);
    }
    if (t == KNOTS) gTotalChunks = A[KNOTS];
}

// Main: 1 wave = 16 samples OF THE SAME KNOT -> all table reads wave-uniform.
// lane: sl=lane&15 (sample), grp=lane>>4 (k/h group).
__global__ __launch_bounds__(256) void hyper_main(
    const float* __restrict__ coords, const float* __restrict__ B1,
    const float* __restrict__ B3, float* __restrict__ out) {
    const int tid = threadIdx.x;
    const int wid = tid >> 6;
    const int l = tid & 63;
    const int grp = l >> 4;
    const int sl = l & 15;

    const int id = blockIdx.x * 4 + wid;
    if (id >= gTotalChunks) return;
    const int4 ck = chunkTab[id];
    const int j    = __builtin_amdgcn_readfirstlane(ck.x);
    const int base = __builtin_amdgcn_readfirstlane(ck.y);
    const int cnt  = __builtin_amdgcn_readfirstlane(ck.z);

    const int sidx = bucket[base + (sl < cnt ? sl : 0)];
    const float2 c = ((const float2*)coords)[sidx];

    const int k1 = grp * 8;
    const int k2 = 32 + grp * 8;
    const unsigned* __restrict__ tb = TBL;

    // ---- wave-uniform table loads (broadcast; single txn each) ----
    const uint4* w1p = (const uint4*)(tb + W1_OFF + j * 64);
    const uint4 wA = w1p[2 * grp],     wA2 = w1p[2 * grp + 1];
    const uint4 wB = w1p[8 + 2 * grp], wB2 = w1p[8 + 2 * grp + 1];
    const uint4* a2p = (const uint4*)(tb + A2_OFF + j * 128);
    uint4 a2r1[4], a2r2[4];
    #pragma unroll
    for (int r = 0; r < 4; ++r) {
        a2r1[r] = a2p[r * 8 + grp];
        a2r2[r] = a2p[r * 8 + 4 + grp];
    }
    const float4 bA0 = *(const float4*)(B1 + k1), bA1 = *(const float4*)(B1 + k1 + 4);
    const float4 bB0 = *(const float4*)(B1 + k2), bB1 = *(const float4*)(B1 + k2 + 4);
    const uint4* afp = (const uint4*)(tb + W2F_OFF);
    uint4 af[8];
    #pragma unroll
    for (int f = 0; f < 8; ++f) af[f] = afp[f * 64 + l];

    // ---- x1 for this lane's 16 k-values ----
    float x1a[8], x1b[8];
    {
        float2 e;
        e = up2(wA.x);  x1a[0] = tanh_fast(fmaf(c.x, e.x, fmaf(c.y, e.y, bA0.x)));
        e = up2(wA.y);  x1a[1] = tanh_fast(fmaf(c.x, e.x, fmaf(c.y, e.y, bA0.y)));
        e = up2(wA.z);  x1a[2] = tanh_fast(fmaf(c.x, e.x, fmaf(c.y, e.y, bA0.z)));
        e = up2(wA.w);  x1a[3] = tanh_fast(fmaf(c.x, e.x, fmaf(c.y, e.y, bA0.w)));
        e = up2(wA2.x); x1a[4] = tanh_fast(fmaf(c.x, e.x, fmaf(c.y, e.y, bA1.x)));
        e = up2(wA2.y); x1a[5] = tanh_fast(fmaf(c.x, e.x, fmaf(c.y, e.y, bA1.y)));
        e = up2(wA2.z); x1a[6] = tanh_fast(fmaf(c.x, e.x, fmaf(c.y, e.y, bA1.z)));
        e = up2(wA2.w); x1a[7] = tanh_fast(fmaf(c.x, e.x, fmaf(c.y, e.y, bA1.w)));
        e = up2(wB.x);  x1b[0] = tanh_fast(fmaf(c.x, e.x, fmaf(c.y, e.y, bB0.x)));
        e = up2(wB.y);  x1b[1] = tanh_fast(fmaf(c.x, e.x, fmaf(c.y, e.y, bB0.y)));
        e = up2(wB.z);  x1b[2] = tanh_fast(fmaf(c.x, e.x, fmaf(c.y, e.y, bB0.z)));
        e = up2(wB.w);  x1b[3] = tanh_fast(fmaf(c.x, e.x, fmaf(c.y, e.y, bB0.w)));
        e = up2(wB2.x); x1b[4] = tanh_fast(fmaf(c.x, e.x, fmaf(c.y, e.y, bB1.x)));
        e = up2(wB2.y); x1b[5] = tanh_fast(fmaf(c.x, e.x, fmaf(c.y, e.y, bB1.y)));
        e = up2(wB2.z); x1b[6] = tanh_fast(fmaf(c.x, e.x, fmaf(c.y, e.y, bB1.z)));
        e = up2(wB2.w); x1b[7] = tanh_fast(fmaf(c.x, e.x, fmaf(c.y, e.y, bB1.w)));
    }
    uint4 x1p1, x1p2;
    x1p1.x = packh2(x1a[0], x1a[1]); x1p1.y = packh2(x1a[2], x1a[3]);
    x1p1.z = packh2(x1a[4], x1a[5]); x1p1.w = packh2(x1a[6], x1a[7]);
    x1p2.x = packh2(x1b[0], x1b[1]); x1p2.y = packh2(x1b[2], x1b[3]);
    x1p2.z = packh2(x1b[4], x1b[5]); x1p2.w = packh2(x1b[6], x1b[7]);
    const half8 xb1 = __builtin_bit_cast(half8, x1p1);
    const half8 xb2 = __builtin_bit_cast(half8, x1p2);

    // ---- W2 @ X1 : 8 MFMAs, D[h=hb*16+4*grp+reg][s=sl] ----
    f32x4 acc[4];
    #pragma unroll
    for (int hb = 0; hb < 4; ++hb) {
        acc[hb] = __builtin_amdgcn_mfma_f32_16x16x32_f16(
            __builtin_bit_cast(half8, af[hb]), xb1, (f32x4){0.f, 0.f, 0.f, 0.f}, 0, 0, 0);
        acc[hb] = __builtin_amdgcn_mfma_f32_16x16x32_f16(
            __builtin_bit_cast(half8, af[4 + hb]), xb2, acc[hb], 0, 0, 0);
    }

    // ---- t2[r] = sum_h a2[r][h] x1[h] ----
    float t2[4];
    #pragma unroll
    for (int r = 0; r < 4; ++r) {
        float v = 0.f;
        v = fdot2u(a2r1[r].x, x1p1.x, v); v = fdot2u(a2r1[r].y, x1p1.y, v);
        v = fdot2u(a2r1[r].z, x1p1.z, v); v = fdot2u(a2r1[r].w, x1p1.w, v);
        v = fdot2u(a2r2[r].x, x1p2.x, v); v = fdot2u(a2r2[r].y, x1p2.y, v);
        v = fdot2u(a2r2[r].z, x1p2.z, v); v = fdot2u(a2r2[r].w, x1p2.w, v);
        v += __shfl_xor(v, 16);
        v += __shfl_xor(v, 32);
        t2[r] = v;
    }
    const unsigned tp01 = packh2(t2[0], t2[1]);
    const unsigned tp23 = packh2(t2[2], t2[3]);

    // ---- x2 + folded output (merged epilogue records) ----
    float osum = 0.f;
    #pragma unroll
    for (int hb = 0; hb < 4; ++hb) {
        const int hbase = hb * 16 + 4 * grp;
        const uint4* ep = (const uint4*)(tb + EP_OFF + j * 192 + hbase * 3);
        const uint4 e0 = ep[0], e1 = ep[1], e2 = ep[2];
        const float2 wb0 = up2(e0.z), wb1 = up2(e1.y), wb2 = up2(e2.x), wb3 = up2(e2.w);
        const float x20 = tanh_fast(acc[hb][0] + fdot2u(e0.x, tp01, fdot2u(e0.y, tp23, wb0.y)));
        const float x21 = tanh_fast(acc[hb][1] + fdot2u(e0.w, tp01, fdot2u(e1.x, tp23, wb1.y)));
        const float x22 = tanh_fast(acc[hb][2] + fdot2u(e1.z, tp01, fdot2u(e1.w, tp23, wb2.y)));
        const float x23 = tanh_fast(acc[hb][3] + fdot2u(e2.y, tp01, fdot2u(e2.z, tp23, wb3.y)));
        osum = fmaf(wb0.x, x20, fmaf(wb1.x, x21, fmaf(wb2.x, x22, fmaf(wb3.x, x23, osum))));
    }
    osum += __shfl_xor(osum, 16);
    osum += __shfl_xor(osum, 32);

    if (grp == 0 && sl < cnt) out[sidx] = osum + B3[0];
}

extern "C" void kernel_launch(void* const* d_in, const int* in_sizes, int n_in,
                              void* d_out, int out_size, void* d_ws, size_t ws_size,
                              hipStream_t stream) {
    const float* coords = (const float*)d_in[0];
    const float* param  = (const float*)d_in[1];
    const float* W1  = (const float*)d_in[2];
    const float* B1  = (const float*)d_in[3];
    const float* W2  = (const float*)d_in[4];
    const float* B2  = (const float*)d_in[5];
    const float* W3  = (const float*)d_in[6];
    const float* B3  = (const float*)d_in[7];
    const float* Wh1 = (const float*)d_in[8];
    const float* Bh1 = (const float*)d_in[9];
    const float* Wh2 = (const float*)d_in[10];
    const float* Bh2 = (const float*)d_in[11];
    float* out = (float*)d_out;
    const int n = out_size;                 // 32768 samples

    build_eff_kernel<<<NKNOT, 256, 0, stream>>>(Wh1, Bh1, Wh2, Bh2, W1, W3, W2, B2);
    scatter_kernel<<<(n + 255) / 256, 256, 0, stream>>>(param, n);
    scan_kernel<<<1, 320, 0, stream>>>();

    const int maxChunks = (n + 15) / 16 + NKNOT;
    hyper_main<<<(maxChunks + 3) / 4, 256, 0, stream>>>(coords, B1, B3, out);
}

// Round 10
// 28.474 us; speedup vs baseline: 1.7932x; 1.7932x over previous
//
#include <hip/hip_runtime.h>

#define HID 64
#define NROWS 1036
#define KNOTS 256            // nearest-neighbor: 257 knots, p_j = j/256
#define NKNOT (KNOTS + 1)

// One 1552-byte record per knot (stride 97*16B: odd multiple of 16B, NOT a
// multiple of 256B -> 16 distinct-j gathers spread across L2 channel slots).
// u32-unit offsets inside a record:
#define W1R 0      // [h]        f16x2 {w1e0,w1e1}          (64 u32)
#define A2R 64     // [r*32+hp]  f16x2 a2 pairs             (128 u32)
#define EPR 192    // [h*3]      {b2r01, b2r23, (w3,B2)}    (192 u32)
#define REC 388    // 1552 B record stride (384 used + 4 pad)

__device__ __align__(16) unsigned TBL[NKNOT * REC];
__device__ __align__(16) uint4 W2F[512];     // W2 MFMA A-frags [kb*4+hb][lane]

typedef _Float16 half2v __attribute__((ext_vector_type(2)));
typedef _Float16 half8  __attribute__((ext_vector_type(8)));
typedef float    f32x4  __attribute__((ext_vector_type(4)));

__device__ inline unsigned packh2(float a, float b) {
    half2v v; v.x = (_Float16)a; v.y = (_Float16)b;
    return __builtin_bit_cast(unsigned, v);
}
__device__ inline float2 up2(unsigned u) {
    half2v v = __builtin_bit_cast(half2v, u);
    return make_float2((float)v.x, (float)v.y);
}
__device__ inline float fdot2u(unsigned a, unsigned b, float c) {
#if defined(__has_builtin) && __has_builtin(__builtin_amdgcn_fdot2)
    return __builtin_amdgcn_fdot2(__builtin_bit_cast(half2v, a),
                                  __builtin_bit_cast(half2v, b), c, false);
#else
    half2v av = __builtin_bit_cast(half2v, a);
    half2v bv = __builtin_bit_cast(half2v, b);
    return fmaf((float)av.x, (float)bv.x, fmaf((float)av.y, (float)bv.y, c));
#endif
}
__device__ inline float tanh_fast(float x) {
    return 1.0f - __fdividef(2.0f, __expf(2.0f * x) + 1.0f);
}

// Build: one block per knot. g[1036] in LDS, fold into the per-knot record.
// Block 0 also packs the W2 MFMA A-fragments.
__global__ __launch_bounds__(256) void build_eff_kernel(
    const float* __restrict__ Wh1, const float* __restrict__ Bh1,
    const float* __restrict__ Wh2, const float* __restrict__ Bh2,
    const float* __restrict__ W1,  const float* __restrict__ W3,
    const float* __restrict__ W2,  const float* __restrict__ B2) {
    __shared__ float h[HID];
    __shared__ float g[NROWS];
    const int j = blockIdx.x;                      // 0..256
    const float p = (float)j / (float)KNOTS;
    const int t = threadIdx.x;
    if (t < HID) h[t] = tanhf(fmaf(p, Wh1[t], Bh1[t]));
    __syncthreads();
    for (int i = t; i < NROWS; i += 256) {
        const float4* row = (const float4*)(Wh2 + i * HID);
        float a0 = 0.f, a1 = 0.f, a2 = 0.f, a3 = 0.f;
        #pragma unroll
        for (int q = 0; q < 16; ++q) {
            float4 w = row[q];
            a0 = fmaf(w.x, h[4 * q + 0], a0);
            a1 = fmaf(w.y, h[4 * q + 1], a1);
            a2 = fmaf(w.z, h[4 * q + 2], a2);
            a3 = fmaf(w.w, h[4 * q + 3], a3);
        }
        g[i] = Bh2[i] + (a0 + a1) + (a2 + a3);
    }
    __syncthreads();
    // g: a1[r][c]=g[2r+c], b1[h][r]=g[8+4h+r], a2[r][k]=g[264+64r+k],
    //    b2[h][r]=g[520+4h+r], a3[r][k]=g[776+64r+k], b3[r]=g[1032+r]
    unsigned* tb = TBL + j * REC;
    if (t < HID) {
        const int hh = t;
        const float* b1 = g + 8 + 4 * hh;
        float e0 = W1[2 * hh], e1 = W1[2 * hh + 1];
        #pragma unroll
        for (int r = 0; r < 4; ++r) {
            e0 = fmaf(b1[r], g[2 * r],     e0);
            e1 = fmaf(b1[r], g[2 * r + 1], e1);
        }
        tb[W1R + hh] = packh2(e0, e1);
        float w3e = W3[hh];
        #pragma unroll
        for (int r = 0; r < 4; ++r)
            w3e = fmaf(g[1032 + r], g[776 + 64 * r + hh], w3e);
        tb[EPR + hh * 3 + 0] = packh2(g[520 + 4 * hh],     g[520 + 4 * hh + 1]);
        tb[EPR + hh * 3 + 1] = packh2(g[520 + 4 * hh + 2], g[520 + 4 * hh + 3]);
        tb[EPR + hh * 3 + 2] = packh2(w3e, B2[hh]);
    }
    if (t < 128) {
        const int r = t >> 5, pp = t & 31;
        tb[A2R + t] = packh2(g[264 + 64 * r + 2 * pp], g[264 + 64 * r + 2 * pp + 1]);
    }
    if (j == 0) {
        for (int q = t; q < 512; q += 256) {
            const int f = q >> 6, l = q & 63;
            const int kb = f >> 2, hb = f & 3;
            const int m = l & 15, k0 = (l >> 4) * 8;
            const float* src = W2 + (hb * 16 + m) * HID + kb * 32 + k0;
            half8 v;
            #pragma unroll
            for (int i = 0; i < 8; ++i) v[i] = (_Float16)src[i];
            W2F[q] = __builtin_bit_cast(uint4, v);
        }
    }
}

// Main: 1 wave = 16 samples. lane: sl=lane&15 (sample), grp=lane>>4 (k/h group).
__global__ __launch_bounds__(256) void hyper_main(
    const float* __restrict__ coords, const float* __restrict__ param,
    const float* __restrict__ B1, const float* __restrict__ B3,
    float* __restrict__ out, int n) {
    const int tid = threadIdx.x;
    const int wid = tid >> 6;
    const int l = tid & 63;
    const int grp = l >> 4;
    const int sl = l & 15;

    const int s0 = blockIdx.x * 64 + wid * 16;
    int s = s0 + sl;
    if (s >= n) s = n - 1;

    const float p = param[s];
    const float2 c = ((const float2*)coords)[s];
    int j = (int)fmaf(p, (float)KNOTS, 0.5f);
    j = max(0, min(KNOTS, j));

    const int k1 = grp * 8;
    const int k2 = 32 + grp * 8;
    const unsigned* __restrict__ tb = TBL + j * REC;   // per-lane record base

    // ---- issue ALL gathers up front (latency overlaps x1/MFMA compute) ----
    const uint4* w1p = (const uint4*)(tb + W1R);
    const uint4 wA = w1p[2 * grp],     wA2 = w1p[2 * grp + 1];
    const uint4 wB = w1p[8 + 2 * grp], wB2 = w1p[8 + 2 * grp + 1];
    const uint4* a2p = (const uint4*)(tb + A2R);
    uint4 a2r1[4], a2r2[4];
    #pragma unroll
    for (int r = 0; r < 4; ++r) {
        a2r1[r] = a2p[r * 8 + grp];
        a2r2[r] = a2p[r * 8 + 4 + grp];
    }
    const uint4* epp = (const uint4*)(tb + EPR);
    uint4 ep[4][3];
    #pragma unroll
    for (int hb = 0; hb < 4; ++hb) {
        ep[hb][0] = epp[3 * grp + 12 * hb + 0];
        ep[hb][1] = epp[3 * grp + 12 * hb + 1];
        ep[hb][2] = epp[3 * grp + 12 * hb + 2];
    }
    // j-independent (L2-hot) pieces
    const float4 bA0 = *(const float4*)(B1 + k1), bA1 = *(const float4*)(B1 + k1 + 4);
    const float4 bB0 = *(const float4*)(B1 + k2), bB1 = *(const float4*)(B1 + k2 + 4);
    uint4 af[8];
    #pragma unroll
    for (int f = 0; f < 8; ++f) af[f] = W2F[f * 64 + l];

    // ---- x1 for this lane's 16 k-values ----
    float x1a[8], x1b[8];
    {
        float2 e;
        e = up2(wA.x);  x1a[0] = tanh_fast(fmaf(c.x, e.x, fmaf(c.y, e.y, bA0.x)));
        e = up2(wA.y);  x1a[1] = tanh_fast(fmaf(c.x, e.x, fmaf(c.y, e.y, bA0.y)));
        e = up2(wA.z);  x1a[2] = tanh_fast(fmaf(c.x, e.x, fmaf(c.y, e.y, bA0.z)));
        e = up2(wA.w);  x1a[3] = tanh_fast(fmaf(c.x, e.x, fmaf(c.y, e.y, bA0.w)));
        e = up2(wA2.x); x1a[4] = tanh_fast(fmaf(c.x, e.x, fmaf(c.y, e.y, bA1.x)));
        e = up2(wA2.y); x1a[5] = tanh_fast(fmaf(c.x, e.x, fmaf(c.y, e.y, bA1.y)));
        e = up2(wA2.z); x1a[6] = tanh_fast(fmaf(c.x, e.x, fmaf(c.y, e.y, bA1.z)));
        e = up2(wA2.w); x1a[7] = tanh_fast(fmaf(c.x, e.x, fmaf(c.y, e.y, bA1.w)));
        e = up2(wB.x);  x1b[0] = tanh_fast(fmaf(c.x, e.x, fmaf(c.y, e.y, bB0.x)));
        e = up2(wB.y);  x1b[1] = tanh_fast(fmaf(c.x, e.x, fmaf(c.y, e.y, bB0.y)));
        e = up2(wB.z);  x1b[2] = tanh_fast(fmaf(c.x, e.x, fmaf(c.y, e.y, bB0.z)));
        e = up2(wB.w);  x1b[3] = tanh_fast(fmaf(c.x, e.x, fmaf(c.y, e.y, bB0.w)));
        e = up2(wB2.x); x1b[4] = tanh_fast(fmaf(c.x, e.x, fmaf(c.y, e.y, bB1.x)));
        e = up2(wB2.y); x1b[5] = tanh_fast(fmaf(c.x, e.x, fmaf(c.y, e.y, bB1.y)));
        e = up2(wB2.z); x1b[6] = tanh_fast(fmaf(c.x, e.x, fmaf(c.y, e.y, bB1.z)));
        e = up2(wB2.w); x1b[7] = tanh_fast(fmaf(c.x, e.x, fmaf(c.y, e.y, bB1.w)));
    }
    uint4 x1p1, x1p2;
    x1p1.x = packh2(x1a[0], x1a[1]); x1p1.y = packh2(x1a[2], x1a[3]);
    x1p1.z = packh2(x1a[4], x1a[5]); x1p1.w = packh2(x1a[6], x1a[7]);
    x1p2.x = packh2(x1b[0], x1b[1]); x1p2.y = packh2(x1b[2], x1b[3]);
    x1p2.z = packh2(x1b[4], x1b[5]); x1p2.w = packh2(x1b[6], x1b[7]);
    const half8 xb1 = __builtin_bit_cast(half8, x1p1);
    const half8 xb2 = __builtin_bit_cast(half8, x1p2);

    // ---- W2 @ X1 : 8 MFMAs, D[h=hb*16+4*grp+reg][s=sl] ----
    f32x4 acc[4];
    #pragma unroll
    for (int hb = 0; hb < 4; ++hb) {
        acc[hb] = __builtin_amdgcn_mfma_f32_16x16x32_f16(
            __builtin_bit_cast(half8, af[hb]), xb1, (f32x4){0.f, 0.f, 0.f, 0.f}, 0, 0, 0);
        acc[hb] = __builtin_amdgcn_mfma_f32_16x16x32_f16(
            __builtin_bit_cast(half8, af[4 + hb]), xb2, acc[hb], 0, 0, 0);
    }

    // ---- t2[r] = sum_h a2[r][h] x1[h] ----
    float t2[4];
    #pragma unroll
    for (int r = 0; r < 4; ++r) {
        float v = 0.f;
        v = fdot2u(a2r1[r].x, x1p1.x, v); v = fdot2u(a2r1[r].y, x1p1.y, v);
        v = fdot2u(a2r1[r].z, x1p1.z, v); v = fdot2u(a2r1[r].w, x1p1.w, v);
        v = fdot2u(a2r2[r].x, x1p2.x, v); v = fdot2u(a2r2[r].y, x1p2.y, v);
        v = fdot2u(a2r2[r].z, x1p2.z, v); v = fdot2u(a2r2[r].w, x1p2.w, v);
        v += __shfl_xor(v, 16);
        v += __shfl_xor(v, 32);
        t2[r] = v;
    }
    const unsigned tp01 = packh2(t2[0], t2[1]);
    const unsigned tp23 = packh2(t2[2], t2[3]);

    // ---- x2 + folded output (prefetched epilogue records) ----
    float osum = 0.f;
    #pragma unroll
    for (int hb = 0; hb < 4; ++hb) {
        const uint4 e0 = ep[hb][0], e1 = ep[hb][1], e2 = ep[hb][2];
        const float2 wb0 = up2(e0.z), wb1 = up2(e1.y), wb2 = up2(e2.x), wb3 = up2(e2.w);
        const float x20 = tanh_fast(acc[hb][0] + fdot2u(e0.x, tp01, fdot2u(e0.y, tp23, wb0.y)));
        const float x21 = tanh_fast(acc[hb][1] + fdot2u(e0.w, tp01, fdot2u(e1.x, tp23, wb1.y)));
        const float x22 = tanh_fast(acc[hb][2] + fdot2u(e1.z, tp01, fdot2u(e1.w, tp23, wb2.y)));
        const float x23 = tanh_fast(acc[hb][3] + fdot2u(e2.y, tp01, fdot2u(e2.z, tp23, wb3.y)));
        osum = fmaf(wb0.x, x20, fmaf(wb1.x, x21, fmaf(wb2.x, x22, fmaf(wb3.x, x23, osum))));
    }
    osum += __shfl_xor(osum, 16);
    osum += __shfl_xor(osum, 32);

    if (grp == 0 && (s0 + sl) < n) out[s0 + sl] = osum + B3[0];
}

extern "C" void kernel_launch(void* const* d_in, const int* in_sizes, int n_in,
                              void* d_out, int out_size, void* d_ws, size_t ws_size,
                              hipStream_t stream) {
    const float* coords = (const float*)d_in[0];
    const float* param  = (const float*)d_in[1];
    const float* W1  = (const float*)d_in[2];
    const float* B1  = (const float*)d_in[3];
    const float* W2  = (const float*)d_in[4];
    const float* B2  = (const float*)d_in[5];
    const float* W3  = (const float*)d_in[6];
    const float* B3  = (const float*)d_in[7];
    const float* Wh1 = (const float*)d_in[8];
    const float* Bh1 = (const float*)d_in[9];
    const float* Wh2 = (const float*)d_in[10];
    const float* Bh2 = (const float*)d_in[11];
    float* out = (float*)d_out;
    const int n = out_size;                 // 32768 samples

    build_eff_kernel<<<NKNOT, 256, 0, stream>>>(Wh1, Bh1, Wh2, Bh2, W1, W3, W2, B2);

    const int nblocks = (n + 63) / 64;      // 64 samples per block (4 waves x 16)
    hyper_main<<<nblocks, 256, 0, stream>>>(coords, param, B1, B3, out, n);
}